// Round 8
// baseline (733.640 us; speedup 1.0000x reference)
//
#include <hip/hip_runtime.h>
#include <cstdint>
#include <cstddef>

typedef unsigned short u16;
typedef unsigned int u32;
typedef __attribute__((ext_vector_type(8))) short short8;
typedef __attribute__((ext_vector_type(4))) float floatx4;
typedef __attribute__((ext_vector_type(2))) float float2v;

#define NROWS 38400   // B*T = 64*600

// ---- workspace layout (bytes) ----
#define OFF_FLAG 0u
#define OFF_GI   64u           // [2][38400][120] f32 = 36,864,000
#define OFF_HCAT 36864064u     // [38400][80] f32    = 12,288,000
#define OFF_B1A  49152064u     // [256][576] bf16    =    294,912
#define OFF_B1B  49446976u     // [256][576] bf16    =    294,912
#define OFF_B2   49741888u     // [80][1472] bf16    =    235,520
#define OFF_B3   49977408u     // [272][1472] bf16   =    800,768  (end ~50.78 MB)

template<int N> struct IC { static constexpr int v = N; };

__device__ inline float bf2f(u16 u){ union{u32 i; float f;} v; v.i = ((u32)u)<<16; return v.f; }
__device__ inline u16 f2bf(float f){
  u32 u = __float_as_uint(f);
  return (u16)((u + 0x7FFFu + ((u>>16)&1u)) >> 16);   // RNE
}
__device__ inline float lodf(const void* p, size_t i, int isbf){
  return isbf ? bf2f(((const u16*)p)[i]) : ((const float*)p)[i];
}
__device__ inline float rcpf(float x){ return __builtin_amdgcn_rcpf(x); }
__device__ inline float sigm(float x){ return rcpf(1.0f+__expf(-x)); }
__device__ inline float tanh_(float x){
  float e = __expf(-2.0f*fabsf(x)); float t = (1.0f-e)*rcpf(1.0f+e); return x<0.f ? -t : t;
}

// ============================= detect input dtype (bf16 vs f32) =============================
__global__ void detect_kernel(const u16* __restrict__ xx, int* __restrict__ flag){
  const int l = threadIdx.x;
  const u16 w = xx[2*l];
  const int e = (w>>7)&0xFF;
  const unsigned long long m = __ballot(e >= 100 && e <= 133);
  if (l == 0) *flag = (__popcll(m) >= 32) ? 1 : 0;   // 1 = bf16
}

// ============================= prep: build padded bf16 B^T matrices =============================
__global__ void prep_kernel(const void* __restrict__ f0Wih, const void* __restrict__ b0Wih,
                            const void* __restrict__ k1b, const void* __restrict__ k1s, const void* __restrict__ k1sc,
                            const void* __restrict__ k2b, const void* __restrict__ k2s, const void* __restrict__ k2sc,
                            const int* __restrict__ flag,
                            u16* __restrict__ B1a, u16* __restrict__ B1b,
                            u16* __restrict__ B2, u16* __restrict__ B3)
{
  const int isbf = *flag;
  const int idx = blockIdx.x*256 + threadIdx.x;
  if (idx < 73728){
    const int j = idx/288, k = idx - j*288;
    float w = 0.f;
    if (k < 257 && j < 240)
      w = (j < 120) ? lodf(f0Wih, (size_t)j*257+k, isbf) : lodf(b0Wih, (size_t)(j-120)*257+k, isbf);
    const u16 hi = f2bf(w); const u16 lo = f2bf(w - bf2f(hi));
    B1a[(size_t)j*576 + 2*k] = hi; B1a[(size_t)j*576 + 2*k+1] = hi;
    B1b[(size_t)j*576 + 2*k] = lo; B1b[(size_t)j*576 + 2*k+1] = 0;
  } else if (idx < 132608){
    const int t = idx - 73728; const int n = t/736, m = t - n*736;
    float v = 0.f;
    if (m < 80) v = lodf(k1b, (size_t)n*80+m, isbf);
    else if (m >= 96){ const int m2 = m-96, i = m2>>3, g = m2&7;
      v = lodf(k1s, ((size_t)n*80+i)*8+g, isbf) * lodf(k1sc, (size_t)n*80+i, isbf); }
    const u16 vv = f2bf(v);
    B2[(size_t)n*1472 + 2*m] = vv; B2[(size_t)n*1472 + 2*m+1] = vv;
  } else {
    const int t = idx - 132608; const int n = t/736, m = t - n*736;
    float v = 0.f;
    if (n < 257){
      if (m < 80) v = lodf(k2b, (size_t)n*80+m, isbf);
      else if (m >= 96){ const int m2 = m-96, i = m2>>3, g = m2&7;
        v = lodf(k2s, ((size_t)n*80+i)*8+g, isbf) * lodf(k2sc, (size_t)n*80+i, isbf); }
    }
    const u16 vv = f2bf(v);
    B3[(size_t)n*1472 + 2*m] = vv; B3[(size_t)n*1472 + 2*m+1] = vv;
  }
}

// ============================= G1: gi = x @ Wih^T + bih, MFMA, nt-split across waves =============================
// As padded to 584 u16/row (1168 B = 292 dw == 4 mod 32): 2-way bank aliasing
// on the 16-lane MFMA A-frag reads (free) instead of 8-wide at 576.
__launch_bounds__(256)
__global__ void g1_kernel(const void* __restrict__ x, const u16* __restrict__ B1a, const u16* __restrict__ B1b,
                          const void* __restrict__ f0bih, const void* __restrict__ b0bih,
                          const int* __restrict__ flag, float* __restrict__ gi)
{
  __shared__ __attribute__((aligned(16))) u16 As[32][584];
  const int isbf = *flag;
  const int tid = threadIdx.x;
  const size_t r0 = (size_t)blockIdx.x * 32;
  {
    const int row = tid>>3, kk = tid&7;
    #pragma unroll
    for (int it=0; it<36; ++it){
      const int k = kk + it*8;
      const float v = (k < 257) ? lodf(x, (r0+row)*257 + k, isbf) : 0.f;
      const u16 hi = f2bf(v);
      As[row][2*k] = hi; As[row][2*k+1] = f2bf(v - bf2f(hi));
    }
  }
  __syncthreads();
  const int w = tid>>6, l = tid&63, m16 = l&15, q4 = l>>4;
  // NT=15 split {4,4,4,3}
  const int cnt = (w<3)?4:3;
  const int ntlo = w*4;
  floatx4 acc[4][2];
  #pragma unroll
  for (int j=0;j<4;++j) for (int s=0;s<2;++s){ floatx4 z={0.f,0.f,0.f,0.f}; acc[j][s]=z; }
  #pragma unroll 1
  for (int ks=0; ks<18; ++ks){
    const short8 a0 = *(const short8*)&As[m16][ks*32 + q4*8];
    const short8 a1 = *(const short8*)&As[16+m16][ks*32 + q4*8];
    #pragma unroll
    for (int j=0;j<4;++j){
      if (j < cnt){
        const int nt = ntlo + j;
        const short8 ba = *(const short8*)&B1a[(size_t)(nt*16+m16)*576 + ks*32 + q4*8];
        acc[j][0] = __builtin_amdgcn_mfma_f32_16x16x32_bf16(a0, ba, acc[j][0], 0, 0, 0);
        acc[j][1] = __builtin_amdgcn_mfma_f32_16x16x32_bf16(a1, ba, acc[j][1], 0, 0, 0);
        if (!isbf){
          const short8 bb = *(const short8*)&B1b[(size_t)(nt*16+m16)*576 + ks*32 + q4*8];
          acc[j][0] = __builtin_amdgcn_mfma_f32_16x16x32_bf16(a0, bb, acc[j][0], 0, 0, 0);
          acc[j][1] = __builtin_amdgcn_mfma_f32_16x16x32_bf16(a1, bb, acc[j][1], 0, 0, 0);
        }
      }
    }
  }
  #pragma unroll
  for (int j=0;j<4;++j){
    if (j < cnt){
      const int col = (ntlo+j)*16 + m16;
      if (col < 240){
        const int dsel = (col < 120) ? 0 : 1;
        const int jj = (col < 120) ? col : col-120;
        const float bias = (col < 120) ? lodf(f0bih, col, isbf) : lodf(b0bih, col-120, isbf);
        #pragma unroll
        for (int s=0;s<2;++s){
          #pragma unroll
          for (int rg=0; rg<4; ++rg){
            const size_t row = r0 + s*16 + q4*4 + rg;
            gi[((size_t)dsel*NROWS + row)*120 + jj] = acc[j][s][rg] + bias;
          }
        }
      }
    }
  }
}

// ============================= GRU =============================
#define PIN_W() do { \
    _Pragma("unroll") \
    for (int k_ = 0; k_ < 20; ++k_) \
      asm volatile("" : "+v"(WA[k_]), "+v"(WB[k_]), "+v"(WC[k_])); \
    asm volatile("" : "+v"(bA), "+v"(bB), "+v"(bC)); \
  } while (0)

__device__ inline void stage_chunk32(const char* __restrict__ gid, int4* dst, int c, int d, int bat, int l)
{
  const long long rbase = (long long)bat*600 + (d ? (568 - 32*c) : (32*c));
  const long long base = rbase * 480;
  const long long lim = (long long)NROWS * 480;
  int4 v[15];
  #pragma unroll
  for (int j=0; j<15; ++j){
    const long long off = base + (long long)(j*64 + l)*16;
    int4 z; z.x=0; z.y=0; z.z=0; z.w=0;
    v[j] = (off >= 0 && off+16 <= lim) ? *(const int4*)(gid + off) : z;
  }
  #pragma unroll
  for (int j=0; j<15; ++j) dst[j*64 + l] = v[j];
}

__launch_bounds__(256, 1)
__global__ void gru_kernel(const float* __restrict__ gi,
  const void* __restrict__ f0Whh, const void* __restrict__ f0bhh,
  const void* __restrict__ f1Wih, const void* __restrict__ f1Whh, const void* __restrict__ f1bih, const void* __restrict__ f1bhh,
  const void* __restrict__ b0Whh, const void* __restrict__ b0bhh,
  const void* __restrict__ b1Wih, const void* __restrict__ b1Whh, const void* __restrict__ b1bih, const void* __restrict__ b1bhh,
  const int* __restrict__ flag, float* __restrict__ hcat)
{
  __shared__ int4 chunkbuf[2][960];                                   // 30720 B
  __shared__ __attribute__((aligned(16))) float hbuf[2][64][40];      // 20480 B
  __shared__ __attribute__((aligned(16))) float h0buf[2][4][40];      // 1280 B
  __shared__ __attribute__((aligned(16))) float gi1buf[2][4][3][40];  // 3840 B
  __shared__ __attribute__((aligned(16))) float h0st[40];             // layer0 h state (broadcast row)
  __shared__ __attribute__((aligned(16))) float h1st[40];             // layer1 h state
  const int isbf = *flag;
  const int tid = threadIdx.x, l = tid&63;
  // provably wave-uniform role id (SGPR) -> uniform branches around barriers
  const int w = __builtin_amdgcn_readfirstlane(tid) >> 6;
  const int blk = blockIdx.x, d = blk>>6, bat = blk&63;
  const int li = (l < 40) ? l : 39;
  const char* gid = (const char*)(gi + (size_t)d*NROWS*120);

  // Schedule (152 iterations, one barrier each; chunk = 32 ticks = 8 iters):
  //  w0: i<150        : layer0 cells for ticks 4i..4i+3   (reads chunkbuf[(i>>3)&1])
  //  w1: 1<=i<=150    : layer1 input matvec of h0buf[(i-1)&1]
  //  w2: i>=2         : layer1 cells for ticks 4(i-2)..+3 -> hbuf
  //  w3: (i&7)==0     : stage chunk (i>>3)+1 (<=18); (i&15)==2,i>=18: flush hcat window
  if (w == 3){
    stage_chunk32(gid, &chunkbuf[0][0], 0, d, bat, l);
    __syncthreads();
    #pragma unroll 1
    for (int i=0; i<152; ++i){
      if ((i & 7) == 0){ const int c1 = (i>>3) + 1; if (c1 <= 18) stage_chunk32(gid, &chunkbuf[c1&1][0], c1, d, bat, l); }
      if ((i & 15) == 2 && i >= 18){
        const int m = (i>>4) - 1;        // window m: ticks 64m..64m+63, parity m&1
        const int t0 = 64*m;
        const int4* src = (const int4*)&hbuf[m&1][0][0];
        #pragma unroll
        for (int q=0; q<10; ++q){
          const int f = q*64 + l;
          const int t = f/10, j4 = f - 10*t;
          int4 v = src[t*10 + j4];
          *(int4*)&hcat[((size_t)bat*600 + t0 + t)*80 + d*40 + j4*4] = v;
        }
      }
      __syncthreads();
    }
  } else {
    // ---------------- compute waves: load role weights into VGPR pairs ----------------
    const void *Wsrc = 0, *bsrc = 0;
    if (w == 0){ Wsrc = d ? b0Whh : f0Whh; bsrc = d ? b0bhh : f0bhh; }
    else if (w == 1){ Wsrc = d ? b1Wih : f1Wih; bsrc = d ? b1bih : f1bih; }
    else { Wsrc = d ? b1Whh : f1Whh; bsrc = d ? b1bhh : f1bhh; }

    float2v WA[20], WB[20], WC[20];
    #pragma unroll
    for (int k=0; k<20; ++k){
      WA[k][0] = lodf(Wsrc, (size_t)(     li)*40 + 2*k,   isbf);
      WA[k][1] = lodf(Wsrc, (size_t)(     li)*40 + 2*k+1, isbf);
      WB[k][0] = lodf(Wsrc, (size_t)(40 + li)*40 + 2*k,   isbf);
      WB[k][1] = lodf(Wsrc, (size_t)(40 + li)*40 + 2*k+1, isbf);
      WC[k][0] = lodf(Wsrc, (size_t)(80 + li)*40 + 2*k,   isbf);
      WC[k][1] = lodf(Wsrc, (size_t)(80 + li)*40 + 2*k+1, isbf);
    }
    float bA = lodf(bsrc, li, isbf), bB = lodf(bsrc, 40+li, isbf), bC = lodf(bsrc, 80+li, isbf);
    float hs = 0.f;

    // broadcast matvec via packed fp32 FMA: h read from 160B LDS row with
    // wave-uniform addresses (ds_read_b128 broadcast); 60 v_pk_fma_f32 total.
    auto mv3B = [&](const float* hrow, float& oa, float& ob, float& oc){
      float2v a2 = {bA, 0.f}, b2 = {bB, 0.f}, c2 = {bC, 0.f};
      #pragma unroll
      for (int kq=0; kq<10; ++kq){
        const floatx4 hv = *(const floatx4*)(hrow + kq*4);
        float2v h0; h0[0]=hv[0]; h0[1]=hv[1];
        float2v h1; h1[0]=hv[2]; h1[1]=hv[3];
        asm("v_pk_fma_f32 %0, %1, %2, %0" : "+v"(a2) : "v"(WA[2*kq  ]), "v"(h0));
        asm("v_pk_fma_f32 %0, %1, %2, %0" : "+v"(b2) : "v"(WB[2*kq  ]), "v"(h0));
        asm("v_pk_fma_f32 %0, %1, %2, %0" : "+v"(c2) : "v"(WC[2*kq  ]), "v"(h0));
        asm("v_pk_fma_f32 %0, %1, %2, %0" : "+v"(a2) : "v"(WA[2*kq+1]), "v"(h1));
        asm("v_pk_fma_f32 %0, %1, %2, %0" : "+v"(b2) : "v"(WB[2*kq+1]), "v"(h1));
        asm("v_pk_fma_f32 %0, %1, %2, %0" : "+v"(c2) : "v"(WC[2*kq+1]), "v"(h1));
      }
      oa = a2[0] + a2[1]; ob = b2[0] + b2[1]; oc = c2[0] + c2[1];
    };
    auto cellB = [&](const float* hrow, float hsv, float gA, float gB, float gC) -> float {
      float ar, az, an;
      mv3B(hrow, ar, az, an);
      const float r = sigm(gA + ar), z = sigm(gB + az);
      const float n = tanh_(gC + r*an);
      return (1.f - z)*n + z*hsv;
    };

    if (w == 0){
      if (l < 40) h0st[l] = 0.f;       // own-wave state init (no cross-wave reader)
      __syncthreads();
      #pragma unroll 1
      for (int i=0; i<152; ++i){
        PIN_W();
        if (i < 150){
          const int cc = (i>>3)&1;
          const int ta = (4*i)&31;
          const float* base = (const float*)&chunkbuf[cc][0];
          // hoist all 12 gate inputs for the period (one LDS latency batch)
          float gin[4][3];
          #pragma unroll
          for (int t=0; t<4; ++t){
            const float* r = base + (d ? (31-(ta+t)) : (ta+t))*120;
            gin[t][0]=r[li]; gin[t][1]=r[40+li]; gin[t][2]=r[80+li];
          }
          #pragma unroll
          for (int t=0; t<4; ++t){
            hs = cellB(h0st, hs, gin[t][0], gin[t][1], gin[t][2]);
            if (l < 40){ h0st[l] = hs; h0buf[i&1][t][l] = hs; }
          }
        }
        __syncthreads();
      }
    } else if (w == 1){
      __syncthreads();
      #pragma unroll 1
      for (int i=0; i<152; ++i){
        PIN_W();
        if (i >= 1 && i <= 150){
          const int p = (i-1)&1;
          #pragma unroll
          for (int t=0; t<4; ++t){
            float oa, ob, oc;
            mv3B(&h0buf[p][t][0], oa, ob, oc);
            if (l < 40){
              gi1buf[i&1][t][0][l]=oa; gi1buf[i&1][t][1][l]=ob; gi1buf[i&1][t][2][l]=oc;
            }
          }
        }
        __syncthreads();
      }
    } else {
      if (l < 40) h1st[l] = 0.f;
      __syncthreads();
      #pragma unroll 1
      for (int i=0; i<152; ++i){
        PIN_W();
        if (i >= 2){
          const int p = (i-1)&1;
          // hoist the 12 gate inputs (written by w1 last period; barrier between)
          float gin[4][3];
          #pragma unroll
          for (int t=0; t<4; ++t){
            gin[t][0]=gi1buf[p][t][0][li]; gin[t][1]=gi1buf[p][t][1][li]; gin[t][2]=gi1buf[p][t][2][li];
          }
          const int ta2 = 4*(i-2);
          const int wp = (ta2>>6)&1, sa = ta2&63;
          #pragma unroll
          for (int t=0; t<4; ++t){
            hs = cellB(h1st, hs, gin[t][0], gin[t][1], gin[t][2]);
            if (l < 40){ h1st[l] = hs; hbuf[wp][sa+t][l] = hs; }
          }
        }
        __syncthreads();
      }
    }
  }
  // flush final window (window 9: ticks 576..599, parity 1); all waves have passed
  // the final in-loop barrier (153 barriers each), so hbuf writes are visible.
  if (tid < 240){
    const int t = tid/10, j4 = tid - 10*t;
    const int4* src = (const int4*)&hbuf[1][0][0];
    int4 v = src[t*10 + j4];
    *(int4*)&hcat[((size_t)bat*600 + 576 + t)*80 + d*40 + j4*4] = v;
  }
}

// ============================= KAN: fused kan1+kan2, 32-row tiles =============================
// R7 counters: conflicts 2.47e7->5.36e6 and 278->215us, but MfmaUtil 7.5 /
// VALUBusy 26.6 / HBM 4.8 / Occupancy 14% -> latency-bound with only 2
// blocks/CU (LDS 63.5KB). Fix: 32-row tiles, 1200 blocks; LDS = 32,256B ->
// 5 blocks/CU by LDS; halved acc drops VGPR pressure. xs padded to stride 84
// dw (== 20 mod 32) to kill the residual 4-way spline-read conflicts.
__device__ inline void spline8(float x, float* bs)
{
  float g[12];
  #pragma unroll
  for (int j=0; j<12; ++j) g[j] = (float)(j-3)*0.4f - 1.0f;
  float b0[11];
  #pragma unroll
  for (int j=0; j<11; ++j) b0[j] = (x >= g[j] && x < g[j+1]) ? 1.f : 0.f;
  float b1[10];
  #pragma unroll
  for (int j=0; j<10; ++j)
    b1[j] = (x - g[j])*(1.0f/(g[j+1]-g[j]))*b0[j] + (g[j+2] - x)*(1.0f/(g[j+2]-g[j+1]))*b0[j+1];
  float b2[9];
  #pragma unroll
  for (int j=0; j<9; ++j)
    b2[j] = (x - g[j])*(1.0f/(g[j+2]-g[j]))*b1[j] + (g[j+3] - x)*(1.0f/(g[j+3]-g[j+1]))*b1[j+1];
  #pragma unroll
  for (int j=0; j<8; ++j)
    bs[j] = (x - g[j])*(1.0f/(g[j+3]-g[j]))*b2[j] + (g[j+4] - x)*(1.0f/(g[j+4]-g[j+1]))*b2[j+1];
}

__launch_bounds__(256, 4)
__global__ void kan_fused_kernel(const float* __restrict__ Xin,
                                 const u16* __restrict__ B2mat, const u16* __restrict__ B3mat,
                                 void* __restrict__ Obuf,
                                 const void* __restrict__ slope, const int* __restrict__ flag)
{
  __shared__ __attribute__((aligned(16))) float xs[32][84];       // 10752 B; stride 84 dw == 20 mod 32
  __shared__ __attribute__((aligned(16))) u16 abase[32][200];     // 12800 B (stride 400B == 4 mod 32 dw)
  __shared__ __attribute__((aligned(16))) u16 asp[32][136];       //  8704 B (stride 272B == 4 mod 32 dw)
  const int isbf = *flag;
  const int tid = threadIdx.x;
  const size_t r0 = (size_t)blockIdx.x * 32;
  const int w = tid>>6, l = tid&63, m16 = l&15, q4 = l>>4;

  for (int idx=tid; idx<2560; idx+=256){
    const int row = idx/80, m = idx - row*80;
    xs[row][m] = Xin[r0*80 + idx];
  }
  __syncthreads();

  auto phase = [&](auto ntc, auto fc, const u16* __restrict__ Bmat){
    constexpr int NT   = decltype(ntc)::v;
    constexpr int FINAL = decltype(fc)::v;
    constexpr int MAXC = (NT+3)/4;
    const int cbase = NT>>2, rem = NT&3;
    const int cnt  = cbase + ((w < rem) ? 1 : 0);
    const int ntlo = w*cbase + ((w < rem) ? w : rem);

    short8 bz;
    #pragma unroll
    for (int q=0;q<8;++q) bz[q]=0;
    short8 bcur[MAXC], bnxt[MAXC];
    #pragma unroll
    for (int j=0;j<MAXC;++j){ bcur[j]=bz; bnxt[j]=bz; }

    // prefetch B(base, ks=0) -- hides under silu + barrier
    #pragma unroll
    for (int j=0;j<MAXC;++j) if (j<cnt)
      bcur[j] = *(const short8*)&Bmat[(size_t)((ntlo+j)*16+m16)*1472 + q4*8];

    // silu(xs) -> abase (hi/lo bf16 pairs)
    for (int idx=tid; idx<3072; idx+=256){
      const int row = idx/96, m = idx - row*96;
      float v = 0.f;
      if (m < 80){ const float xv = xs[row][m]; v = xv * sigm(xv); }
      const u16 hi = f2bf(v);
      abase[row][2*m] = hi; abase[row][2*m+1] = f2bf(v - bf2f(hi));
    }
    __syncthreads();

    floatx4 acc[MAXC][2];
    #pragma unroll
    for (int j=0;j<MAXC;++j) for (int s=0;s<2;++s){ floatx4 z={0.f,0.f,0.f,0.f}; acc[j][s]=z; }

    #pragma unroll 1
    for (int ks=0; ks<6; ++ks){
      #pragma unroll
      for (int j=0;j<MAXC;++j) if (j<cnt && ks<5)
        bnxt[j] = *(const short8*)&Bmat[(size_t)((ntlo+j)*16+m16)*1472 + (ks+1)*32 + q4*8];
      short8 a[2];
      #pragma unroll
      for (int s=0;s<2;++s) a[s] = *(const short8*)&abase[s*16+m16][ks*32 + q4*8];
      #pragma unroll
      for (int j=0;j<MAXC;++j){
        if (j < cnt){
          #pragma unroll
          for (int s=0;s<2;++s) acc[j][s] = __builtin_amdgcn_mfma_f32_16x16x32_bf16(a[s], bcur[j], acc[j][s], 0, 0, 0);
        }
      }
      #pragma unroll
      for (int j=0;j<MAXC;++j) bcur[j] = bnxt[j];
    }
    #pragma unroll 1
    for (int c=0; c<10; ++c){
      // prefetch B(c, ks=0) -- hides under spline compute + 2 barriers
      #pragma unroll
      for (int j=0;j<MAXC;++j) if (j<cnt)
        bcur[j] = *(const short8*)&Bmat[(size_t)((ntlo+j)*16+m16)*1472 + 192 + c*128 + q4*8];
      __syncthreads();
      {
        const int row = tid>>3, il = tid&7;   // 256 threads == 32 rows x 8 cols
        const float xv = xs[row][c*8 + il];
        float bs[8]; spline8(xv, bs);
        union { u16 us[16]; short8 v2[2]; } pk;
        #pragma unroll
        for (int j=0; j<8; ++j){ const u16 hi = f2bf(bs[j]); pk.us[2*j] = hi; pk.us[2*j+1] = f2bf(bs[j] - bf2f(hi)); }
        *(short8*)&asp[row][il*16]     = pk.v2[0];
        *(short8*)&asp[row][il*16 + 8] = pk.v2[1];
      }
      __syncthreads();
      #pragma unroll 1
      for (int ks=0; ks<4; ++ks){
        #pragma unroll
        for (int j=0;j<MAXC;++j) if (j<cnt && ks<3)
          bnxt[j] = *(const short8*)&Bmat[(size_t)((ntlo+j)*16+m16)*1472 + 192 + c*128 + (ks+1)*32 + q4*8];
        short8 a[2];
        #pragma unroll
        for (int s=0;s<2;++s) a[s] = *(const short8*)&asp[s*16+m16][ks*32 + q4*8];
        #pragma unroll
        for (int j=0;j<MAXC;++j){
          if (j < cnt){
            #pragma unroll
            for (int s=0;s<2;++s) acc[j][s] = __builtin_amdgcn_mfma_f32_16x16x32_bf16(a[s], bcur[j], acc[j][s], 0, 0, 0);
          }
        }
        #pragma unroll
        for (int j=0;j<MAXC;++j) bcur[j] = bnxt[j];
      }
    }
    // epilogue: kan1 -> overwrite xs in LDS (xs inputs are dead after c=9);
    // kan2 -> activation + store to Obuf
    __syncthreads();   // ensure all waves done reading xs (spline c=9) before overwrite
    #pragma unroll
    for (int j=0;j<MAXC;++j){
      if (j < cnt){
        const int col = (ntlo+j)*16 + m16;
        #pragma unroll
        for (int s=0;s<2;++s){
          #pragma unroll
          for (int rg=0; rg<4; ++rg){
            const int row = s*16 + q4*4 + rg;
            const float v = acc[j][s][rg];
            if constexpr (!FINAL){
              xs[row][col] = v;          // col < 80 for NT=5
            } else {
              if (col < 257){
                const float sl = lodf(slope, col, isbf);
                const float o = 1.2f * sigm(sl*v);
                if (isbf) ((u16*)Obuf)[(r0+row)*257 + col] = f2bf(o);
                else      ((float*)Obuf)[(r0+row)*257 + col] = o;
              }
            }
          }
        }
      }
    }
    __syncthreads();   // xs writes visible before next phase's silu reads
  };

  phase(IC<5>{},  IC<0>{}, B2mat);
  phase(IC<17>{}, IC<1>{}, B3mat);
}

// ============================= launcher =============================
extern "C" void kernel_launch(void* const* d_in, const int* in_sizes, int n_in,
                              void* d_out, int out_size, void* d_ws, size_t ws_size,
                              hipStream_t stream)
{
  (void)in_sizes; (void)n_in; (void)out_size; (void)ws_size;
  const void* x     = d_in[0];
  const void* f0Wih = d_in[2];  const void* f0Whh = d_in[3];
  const void* f0bih = d_in[4];  const void* f0bhh = d_in[5];
  const void* f1Wih = d_in[6];  const void* f1Whh = d_in[7];
  const void* f1bih = d_in[8];  const void* f1bhh = d_in[9];
  const void* b0Wih = d_in[10]; const void* b0Whh = d_in[11];
  const void* b0bih = d_in[12]; const void* b0bhh = d_in[13];
  const void* b1Wih = d_in[14]; const void* b1Whh = d_in[15];
  const void* b1bih = d_in[16]; const void* b1bhh = d_in[17];
  const void* k1b   = d_in[18]; const void* k1s   = d_in[19]; const void* k1sc = d_in[20];
  const void* k2b   = d_in[21]; const void* k2s   = d_in[22]; const void* k2sc = d_in[23];
  const void* slope = d_in[24];

  char* ws = (char*)d_ws;
  int*   flag  = (int*)(ws + OFF_FLAG);
  float* gi    = (float*)(ws + OFF_GI);
  float* hcat  = (float*)(ws + OFF_HCAT);
  u16* B1a = (u16*)(ws + OFF_B1A);
  u16* B1b = (u16*)(ws + OFF_B1B);
  u16* B2  = (u16*)(ws + OFF_B2);
  u16* B3  = (u16*)(ws + OFF_B3);

  detect_kernel<<<1, 64, 0, stream>>>((const u16*)x, flag);
  prep_kernel<<<1300, 256, 0, stream>>>(f0Wih, b0Wih, k1b, k1s, k1sc, k2b, k2s, k2sc, flag, B1a, B1b, B2, B3);
  g1_kernel<<<1200, 256, 0, stream>>>(x, B1a, B1b, f0bih, b0bih, flag, gi);
  gru_kernel<<<128, 256, 0, stream>>>(gi,
      f0Whh, f0bhh, f1Wih, f1Whh, f1bih, f1bhh,
      b0Whh, b0bhh, b1Wih, b1Whh, b1bih, b1bhh, flag, hcat);
  kan_fused_kernel<<<1200, 256, 0, stream>>>(hcat, B2, B3, d_out, slope, flag);
}

// Round 9
// 651.821 us; speedup vs baseline: 1.1255x; 1.1255x over previous
//
#include <hip/hip_runtime.h>
#include <cstdint>
#include <cstddef>

typedef unsigned short u16;
typedef unsigned int u32;
typedef __attribute__((ext_vector_type(8))) short short8;
typedef __attribute__((ext_vector_type(4))) float floatx4;
typedef __attribute__((ext_vector_type(2))) float float2v;

#define NROWS 38400   // B*T = 64*600

// ---- workspace layout (bytes) ----
#define OFF_FLAG 0u
#define OFF_GI   64u           // [2][38400][120] f32 = 36,864,000
#define OFF_HCAT 36864064u     // [38400][80] f32    = 12,288,000
#define OFF_B1A  49152064u     // [256][576] bf16    =    294,912
#define OFF_B1B  49446976u     // [256][576] bf16    =    294,912
#define OFF_B2   49741888u     // [80][1472] bf16    =    235,520
#define OFF_B3   49977408u     // [272][1472] bf16   =    800,768  (end ~50.78 MB)

template<int N> struct IC { static constexpr int v = N; };

__device__ inline float bf2f(u16 u){ union{u32 i; float f;} v; v.i = ((u32)u)<<16; return v.f; }
__device__ inline u16 f2bf(float f){
  u32 u = __float_as_uint(f);
  return (u16)((u + 0x7FFFu + ((u>>16)&1u)) >> 16);   // RNE
}
__device__ inline float lodf(const void* p, size_t i, int isbf){
  return isbf ? bf2f(((const u16*)p)[i]) : ((const float*)p)[i];
}
__device__ inline float rcpf(float x){ return __builtin_amdgcn_rcpf(x); }
__device__ inline float sigm(float x){ return rcpf(1.0f+__expf(-x)); }
__device__ inline float tanh_(float x){
  float e = __expf(-2.0f*fabsf(x)); float t = (1.0f-e)*rcpf(1.0f+e); return x<0.f ? -t : t;
}

// ============================= detect input dtype (bf16 vs f32) =============================
__global__ void detect_kernel(const u16* __restrict__ xx, int* __restrict__ flag){
  const int l = threadIdx.x;
  const u16 w = xx[2*l];
  const int e = (w>>7)&0xFF;
  const unsigned long long m = __ballot(e >= 100 && e <= 133);
  if (l == 0) *flag = (__popcll(m) >= 32) ? 1 : 0;   // 1 = bf16
}

// ============================= prep: build padded bf16 B^T matrices =============================
__global__ void prep_kernel(const void* __restrict__ f0Wih, const void* __restrict__ b0Wih,
                            const void* __restrict__ k1b, const void* __restrict__ k1s, const void* __restrict__ k1sc,
                            const void* __restrict__ k2b, const void* __restrict__ k2s, const void* __restrict__ k2sc,
                            const int* __restrict__ flag,
                            u16* __restrict__ B1a, u16* __restrict__ B1b,
                            u16* __restrict__ B2, u16* __restrict__ B3)
{
  const int isbf = *flag;
  const int idx = blockIdx.x*256 + threadIdx.x;
  if (idx < 73728){
    const int j = idx/288, k = idx - j*288;
    float w = 0.f;
    if (k < 257 && j < 240)
      w = (j < 120) ? lodf(f0Wih, (size_t)j*257+k, isbf) : lodf(b0Wih, (size_t)(j-120)*257+k, isbf);
    const u16 hi = f2bf(w); const u16 lo = f2bf(w - bf2f(hi));
    B1a[(size_t)j*576 + 2*k] = hi; B1a[(size_t)j*576 + 2*k+1] = hi;
    B1b[(size_t)j*576 + 2*k] = lo; B1b[(size_t)j*576 + 2*k+1] = 0;
  } else if (idx < 132608){
    const int t = idx - 73728; const int n = t/736, m = t - n*736;
    float v = 0.f;
    if (m < 80) v = lodf(k1b, (size_t)n*80+m, isbf);
    else if (m >= 96){ const int m2 = m-96, i = m2>>3, g = m2&7;
      v = lodf(k1s, ((size_t)n*80+i)*8+g, isbf) * lodf(k1sc, (size_t)n*80+i, isbf); }
    const u16 vv = f2bf(v);
    B2[(size_t)n*1472 + 2*m] = vv; B2[(size_t)n*1472 + 2*m+1] = vv;
  } else {
    const int t = idx - 132608; const int n = t/736, m = t - n*736;
    float v = 0.f;
    if (n < 257){
      if (m < 80) v = lodf(k2b, (size_t)n*80+m, isbf);
      else if (m >= 96){ const int m2 = m-96, i = m2>>3, g = m2&7;
        v = lodf(k2s, ((size_t)n*80+i)*8+g, isbf) * lodf(k2sc, (size_t)n*80+i, isbf); }
    }
    const u16 vv = f2bf(v);
    B3[(size_t)n*1472 + 2*m] = vv; B3[(size_t)n*1472 + 2*m+1] = vv;
  }
}

// ============================= G1: gi = x @ Wih^T + bih, MFMA, nt-split across waves =============================
// As padded to 584 u16/row (1168 B = 292 dw == 4 mod 32).
__launch_bounds__(256)
__global__ void g1_kernel(const void* __restrict__ x, const u16* __restrict__ B1a, const u16* __restrict__ B1b,
                          const void* __restrict__ f0bih, const void* __restrict__ b0bih,
                          const int* __restrict__ flag, float* __restrict__ gi)
{
  __shared__ __attribute__((aligned(16))) u16 As[32][584];
  const int isbf = *flag;
  const int tid = threadIdx.x;
  const size_t r0 = (size_t)blockIdx.x * 32;
  {
    const int row = tid>>3, kk = tid&7;
    #pragma unroll
    for (int it=0; it<36; ++it){
      const int k = kk + it*8;
      const float v = (k < 257) ? lodf(x, (r0+row)*257 + k, isbf) : 0.f;
      const u16 hi = f2bf(v);
      As[row][2*k] = hi; As[row][2*k+1] = f2bf(v - bf2f(hi));
    }
  }
  __syncthreads();
  const int w = tid>>6, l = tid&63, m16 = l&15, q4 = l>>4;
  // NT=15 split {4,4,4,3}
  const int cnt = (w<3)?4:3;
  const int ntlo = w*4;
  floatx4 acc[4][2];
  #pragma unroll
  for (int j=0;j<4;++j) for (int s=0;s<2;++s){ floatx4 z={0.f,0.f,0.f,0.f}; acc[j][s]=z; }
  #pragma unroll 1
  for (int ks=0; ks<18; ++ks){
    const short8 a0 = *(const short8*)&As[m16][ks*32 + q4*8];
    const short8 a1 = *(const short8*)&As[16+m16][ks*32 + q4*8];
    #pragma unroll
    for (int j=0;j<4;++j){
      if (j < cnt){
        const int nt = ntlo + j;
        const short8 ba = *(const short8*)&B1a[(size_t)(nt*16+m16)*576 + ks*32 + q4*8];
        acc[j][0] = __builtin_amdgcn_mfma_f32_16x16x32_bf16(a0, ba, acc[j][0], 0, 0, 0);
        acc[j][1] = __builtin_amdgcn_mfma_f32_16x16x32_bf16(a1, ba, acc[j][1], 0, 0, 0);
        if (!isbf){
          const short8 bb = *(const short8*)&B1b[(size_t)(nt*16+m16)*576 + ks*32 + q4*8];
          acc[j][0] = __builtin_amdgcn_mfma_f32_16x16x32_bf16(a0, bb, acc[j][0], 0, 0, 0);
          acc[j][1] = __builtin_amdgcn_mfma_f32_16x16x32_bf16(a1, bb, acc[j][1], 0, 0, 0);
        }
      }
    }
  }
  #pragma unroll
  for (int j=0;j<4;++j){
    if (j < cnt){
      const int col = (ntlo+j)*16 + m16;
      if (col < 240){
        const int dsel = (col < 120) ? 0 : 1;
        const int jj = (col < 120) ? col : col-120;
        const float bias = (col < 120) ? lodf(f0bih, col, isbf) : lodf(b0bih, col-120, isbf);
        #pragma unroll
        for (int s=0;s<2;++s){
          #pragma unroll
          for (int rg=0; rg<4; ++rg){
            const size_t row = r0 + s*16 + q4*4 + rg;
            gi[((size_t)dsel*NROWS + row)*120 + jj] = acc[j][s][rg] + bias;
          }
        }
      }
    }
  }
}

// ============================= GRU =============================
#define PIN_W() do { \
    _Pragma("unroll") \
    for (int k_ = 0; k_ < 20; ++k_) \
      asm volatile("" : "+v"(WA[k_]), "+v"(WB[k_]), "+v"(WC[k_])); \
    asm volatile("" : "+v"(bA), "+v"(bB), "+v"(bC)); \
  } while (0)

__device__ inline void stage_chunk32(const char* __restrict__ gid, int4* dst, int c, int d, int bat, int l)
{
  const long long rbase = (long long)bat*600 + (d ? (568 - 32*c) : (32*c));
  const long long base = rbase * 480;
  const long long lim = (long long)NROWS * 480;
  int4 v[15];
  #pragma unroll
  for (int j=0; j<15; ++j){
    const long long off = base + (long long)(j*64 + l)*16;
    int4 z; z.x=0; z.y=0; z.z=0; z.w=0;
    v[j] = (off >= 0 && off+16 <= lim) ? *(const int4*)(gid + off) : z;
  }
  #pragma unroll
  for (int j=0; j<15; ++j) dst[j*64 + l] = v[j];
}

__launch_bounds__(256, 1)
__global__ void gru_kernel(const float* __restrict__ gi,
  const void* __restrict__ f0Whh, const void* __restrict__ f0bhh,
  const void* __restrict__ f1Wih, const void* __restrict__ f1Whh, const void* __restrict__ f1bih, const void* __restrict__ f1bhh,
  const void* __restrict__ b0Whh, const void* __restrict__ b0bhh,
  const void* __restrict__ b1Wih, const void* __restrict__ b1Whh, const void* __restrict__ b1bih, const void* __restrict__ b1bhh,
  const int* __restrict__ flag, float* __restrict__ hcat)
{
  __shared__ int4 chunkbuf[2][960];                                   // 30720 B
  __shared__ __attribute__((aligned(16))) float hbuf[2][64][40];      // 20480 B
  __shared__ __attribute__((aligned(16))) float h0buf[2][4][40];      // 1280 B
  __shared__ __attribute__((aligned(16))) float gi1buf[2][4][3][40];  // 3840 B
  __shared__ __attribute__((aligned(16))) float h0st[40];             // layer0 h state (broadcast row)
  __shared__ __attribute__((aligned(16))) float h1st[40];             // layer1 h state
  const int isbf = *flag;
  const int tid = threadIdx.x, l = tid&63;
  // provably wave-uniform role id (SGPR) -> uniform branches around barriers
  const int w = __builtin_amdgcn_readfirstlane(tid) >> 6;
  const int blk = blockIdx.x, d = blk>>6, bat = blk&63;
  const int li = (l < 40) ? l : 39;
  const char* gid = (const char*)(gi + (size_t)d*NROWS*120);

  // Schedule (152 iterations, one barrier each; chunk = 32 ticks = 8 iters):
  //  w0: i<150        : layer0 cells for ticks 4i..4i+3   (reads chunkbuf[(i>>3)&1])
  //  w1: 1<=i<=150    : layer1 input matvec of h0buf[(i-1)&1]
  //  w2: i>=2         : layer1 cells for ticks 4(i-2)..+3 -> hbuf
  //  w3: (i&7)==0     : stage chunk (i>>3)+1 (<=18); (i&15)==2,i>=18: flush hcat window
  if (w == 3){
    stage_chunk32(gid, &chunkbuf[0][0], 0, d, bat, l);
    __syncthreads();
    #pragma unroll 1
    for (int i=0; i<152; ++i){
      if ((i & 7) == 0){ const int c1 = (i>>3) + 1; if (c1 <= 18) stage_chunk32(gid, &chunkbuf[c1&1][0], c1, d, bat, l); }
      if ((i & 15) == 2 && i >= 18){
        const int m = (i>>4) - 1;        // window m: ticks 64m..64m+63, parity m&1
        const int t0 = 64*m;
        const int4* src = (const int4*)&hbuf[m&1][0][0];
        #pragma unroll
        for (int q=0; q<10; ++q){
          const int f = q*64 + l;
          const int t = f/10, j4 = f - 10*t;
          int4 v = src[t*10 + j4];
          *(int4*)&hcat[((size_t)bat*600 + t0 + t)*80 + d*40 + j4*4] = v;
        }
      }
      __syncthreads();
    }
  } else {
    // ---------------- compute waves: load role weights into VGPR pairs ----------------
    const void *Wsrc = 0, *bsrc = 0;
    if (w == 0){ Wsrc = d ? b0Whh : f0Whh; bsrc = d ? b0bhh : f0bhh; }
    else if (w == 1){ Wsrc = d ? b1Wih : f1Wih; bsrc = d ? b1bih : f1bih; }
    else { Wsrc = d ? b1Whh : f1Whh; bsrc = d ? b1bhh : f1bhh; }

    float2v WA[20], WB[20], WC[20];
    #pragma unroll
    for (int k=0; k<20; ++k){
      WA[k][0] = lodf(Wsrc, (size_t)(     li)*40 + 2*k,   isbf);
      WA[k][1] = lodf(Wsrc, (size_t)(     li)*40 + 2*k+1, isbf);
      WB[k][0] = lodf(Wsrc, (size_t)(40 + li)*40 + 2*k,   isbf);
      WB[k][1] = lodf(Wsrc, (size_t)(40 + li)*40 + 2*k+1, isbf);
      WC[k][0] = lodf(Wsrc, (size_t)(80 + li)*40 + 2*k,   isbf);
      WC[k][1] = lodf(Wsrc, (size_t)(80 + li)*40 + 2*k+1, isbf);
    }
    float bA = lodf(bsrc, li, isbf), bB = lodf(bsrc, 40+li, isbf), bC = lodf(bsrc, 80+li, isbf);
    float hs = 0.f;

    // broadcast matvec via packed fp32 FMA: h read from 160B LDS row with
    // wave-uniform addresses (ds_read_b128 broadcast); 60 v_pk_fma_f32 total.
    auto mv3B = [&](const float* hrow, float& oa, float& ob, float& oc){
      float2v a2 = {bA, 0.f}, b2 = {bB, 0.f}, c2 = {bC, 0.f};
      #pragma unroll
      for (int kq=0; kq<10; ++kq){
        const floatx4 hv = *(const floatx4*)(hrow + kq*4);
        float2v h0; h0[0]=hv[0]; h0[1]=hv[1];
        float2v h1; h1[0]=hv[2]; h1[1]=hv[3];
        asm("v_pk_fma_f32 %0, %1, %2, %0" : "+v"(a2) : "v"(WA[2*kq  ]), "v"(h0));
        asm("v_pk_fma_f32 %0, %1, %2, %0" : "+v"(b2) : "v"(WB[2*kq  ]), "v"(h0));
        asm("v_pk_fma_f32 %0, %1, %2, %0" : "+v"(c2) : "v"(WC[2*kq  ]), "v"(h0));
        asm("v_pk_fma_f32 %0, %1, %2, %0" : "+v"(a2) : "v"(WA[2*kq+1]), "v"(h1));
        asm("v_pk_fma_f32 %0, %1, %2, %0" : "+v"(b2) : "v"(WB[2*kq+1]), "v"(h1));
        asm("v_pk_fma_f32 %0, %1, %2, %0" : "+v"(c2) : "v"(WC[2*kq+1]), "v"(h1));
      }
      oa = a2[0] + a2[1]; ob = b2[0] + b2[1]; oc = c2[0] + c2[1];
    };
    auto cellB = [&](const float* hrow, float hsv, float gA, float gB, float gC) -> float {
      float ar, az, an;
      mv3B(hrow, ar, az, an);
      const float r = sigm(gA + ar), z = sigm(gB + az);
      const float n = tanh_(gC + r*an);
      return (1.f - z)*n + z*hsv;
    };

    if (w == 0){
      if (l < 40) h0st[l] = 0.f;       // own-wave state init (no cross-wave reader)
      __syncthreads();
      #pragma unroll 1
      for (int i=0; i<152; ++i){
        PIN_W();
        if (i < 150){
          const int cc = (i>>3)&1;
          const int ta = (4*i)&31;
          const float* base = (const float*)&chunkbuf[cc][0];
          // hoist all 12 gate inputs for the period (one LDS latency batch)
          float gin[4][3];
          #pragma unroll
          for (int t=0; t<4; ++t){
            const float* r = base + (d ? (31-(ta+t)) : (ta+t))*120;
            gin[t][0]=r[li]; gin[t][1]=r[40+li]; gin[t][2]=r[80+li];
          }
          #pragma unroll
          for (int t=0; t<4; ++t){
            hs = cellB(h0st, hs, gin[t][0], gin[t][1], gin[t][2]);
            if (l < 40){ h0st[l] = hs; h0buf[i&1][t][l] = hs; }
          }
        }
        __syncthreads();
      }
    } else if (w == 1){
      __syncthreads();
      #pragma unroll 1
      for (int i=0; i<152; ++i){
        PIN_W();
        if (i >= 1 && i <= 150){
          const int p = (i-1)&1;
          #pragma unroll
          for (int t=0; t<4; ++t){
            float oa, ob, oc;
            mv3B(&h0buf[p][t][0], oa, ob, oc);
            if (l < 40){
              gi1buf[i&1][t][0][l]=oa; gi1buf[i&1][t][1][l]=ob; gi1buf[i&1][t][2][l]=oc;
            }
          }
        }
        __syncthreads();
      }
    } else {
      if (l < 40) h1st[l] = 0.f;
      __syncthreads();
      #pragma unroll 1
      for (int i=0; i<152; ++i){
        PIN_W();
        if (i >= 2){
          const int p = (i-1)&1;
          // hoist the 12 gate inputs (written by w1 last period; barrier between)
          float gin[4][3];
          #pragma unroll
          for (int t=0; t<4; ++t){
            gin[t][0]=gi1buf[p][t][0][li]; gin[t][1]=gi1buf[p][t][1][li]; gin[t][2]=gi1buf[p][t][2][li];
          }
          const int ta2 = 4*(i-2);
          const int wp = (ta2>>6)&1, sa = ta2&63;
          #pragma unroll
          for (int t=0; t<4; ++t){
            hs = cellB(h1st, hs, gin[t][0], gin[t][1], gin[t][2]);
            if (l < 40){ h1st[l] = hs; hbuf[wp][sa+t][l] = hs; }
          }
        }
        __syncthreads();
      }
    }
  }
  // flush final window (window 9: ticks 576..599, parity 1); all waves have passed
  // the final in-loop barrier (153 barriers each), so hbuf writes are visible.
  if (tid < 240){
    const int t = tid/10, j4 = tid - 10*t;
    const int4* src = (const int4*)&hbuf[1][0][0];
    int4 v = src[t*10 + j4];
    *(int4*)&hcat[((size_t)bat*600 + 576 + t)*80 + d*40 + j4*4] = v;
  }
}

// ============================= KAN: fused kan1+kan2, 64-row tiles, asp aliased onto abase ====
// R8 post-mortem: 32-row tiles REGRESSED (215->307us): FETCH doubled (each of
// 2x blocks streams full B2/B3) and per-block MFMA work halved vs unchanged
// per-ks load latency. Revert to 64 rows / 600 blocks. Occupancy fix without
// shrinking the tile: asp is only live in the c-loop, abase only in the
// preceding 6-ks loop (barrier-separated) -> ALIAS asp onto abase's storage.
// LDS 64.5KB -> 47.1KB -> 3 blocks/CU (12 waves/CU, +50% TLP to fill the
// B-load latency).
__device__ inline void spline8(float x, float* bs)
{
  float g[12];
  #pragma unroll
  for (int j=0; j<12; ++j) g[j] = (float)(j-3)*0.4f - 1.0f;
  float b0[11];
  #pragma unroll
  for (int j=0; j<11; ++j) b0[j] = (x >= g[j] && x < g[j+1]) ? 1.f : 0.f;
  float b1[10];
  #pragma unroll
  for (int j=0; j<10; ++j)
    b1[j] = (x - g[j])*(1.0f/(g[j+1]-g[j]))*b0[j] + (g[j+2] - x)*(1.0f/(g[j+2]-g[j+1]))*b0[j+1];
  float b2[9];
  #pragma unroll
  for (int j=0; j<9; ++j)
    b2[j] = (x - g[j])*(1.0f/(g[j+2]-g[j]))*b1[j] + (g[j+3] - x)*(1.0f/(g[j+3]-g[j+1]))*b1[j+1];
  #pragma unroll
  for (int j=0; j<8; ++j)
    bs[j] = (x - g[j])*(1.0f/(g[j+3]-g[j]))*b2[j] + (g[j+4] - x)*(1.0f/(g[j+4]-g[j+1]))*b2[j+1];
}

__launch_bounds__(256)
__global__ void kan_fused_kernel(const float* __restrict__ Xin,
                                 const u16* __restrict__ B2mat, const u16* __restrict__ B3mat,
                                 void* __restrict__ Obuf,
                                 const void* __restrict__ slope, const int* __restrict__ flag)
{
  __shared__ __attribute__((aligned(16))) float xs[64][84];       // 21504 B; stride 84 dw == 20 mod 32
  __shared__ __attribute__((aligned(16))) u16 abase[64][200];     // 25600 B (stride 100 dw == 4 mod 32)
  // asp aliases abase: only one is live at a time (barrier-separated phases).
  // asp stride 136 u16 = 68 dw == 4 mod 32; region 17408 B < 25600 B.
  u16 (*asp)[136] = (u16(*)[136])&abase[0][0];
  const int isbf = *flag;
  const int tid = threadIdx.x;
  const size_t r0 = (size_t)blockIdx.x * 64;
  const int w = tid>>6, l = tid&63, m16 = l&15, q4 = l>>4;

  for (int idx=tid; idx<5120; idx+=256){
    const int row = idx/80, m = idx - row*80;
    xs[row][m] = Xin[r0*80 + idx];
  }
  __syncthreads();

  auto phase = [&](auto ntc, auto fc, const u16* __restrict__ Bmat){
    constexpr int NT   = decltype(ntc)::v;
    constexpr int FINAL = decltype(fc)::v;
    constexpr int MAXC = (NT+3)/4;
    const int cbase = NT>>2, rem = NT&3;
    const int cnt  = cbase + ((w < rem) ? 1 : 0);
    const int ntlo = w*cbase + ((w < rem) ? w : rem);

    short8 bz;
    #pragma unroll
    for (int q=0;q<8;++q) bz[q]=0;
    short8 bcur[MAXC], bnxt[MAXC];
    #pragma unroll
    for (int j=0;j<MAXC;++j){ bcur[j]=bz; bnxt[j]=bz; }

    // prefetch B(base, ks=0) -- hides under silu + barrier
    #pragma unroll
    for (int j=0;j<MAXC;++j) if (j<cnt)
      bcur[j] = *(const short8*)&Bmat[(size_t)((ntlo+j)*16+m16)*1472 + q4*8];

    // silu(xs) -> abase (hi/lo bf16 pairs)
    for (int idx=tid; idx<6144; idx+=256){
      const int row = idx/96, m = idx - row*96;
      float v = 0.f;
      if (m < 80){ const float xv = xs[row][m]; v = xv * sigm(xv); }
      const u16 hi = f2bf(v);
      abase[row][2*m] = hi; abase[row][2*m+1] = f2bf(v - bf2f(hi));
    }
    __syncthreads();

    floatx4 acc[MAXC][4];
    #pragma unroll
    for (int j=0;j<MAXC;++j) for (int s=0;s<4;++s){ floatx4 z={0.f,0.f,0.f,0.f}; acc[j][s]=z; }

    #pragma unroll 1
    for (int ks=0; ks<6; ++ks){
      #pragma unroll
      for (int j=0;j<MAXC;++j) if (j<cnt && ks<5)
        bnxt[j] = *(const short8*)&Bmat[(size_t)((ntlo+j)*16+m16)*1472 + (ks+1)*32 + q4*8];
      short8 a[4];
      #pragma unroll
      for (int s=0;s<4;++s) a[s] = *(const short8*)&abase[s*16+m16][ks*32 + q4*8];
      #pragma unroll
      for (int j=0;j<MAXC;++j){
        if (j < cnt){
          #pragma unroll
          for (int s=0;s<4;++s) acc[j][s] = __builtin_amdgcn_mfma_f32_16x16x32_bf16(a[s], bcur[j], acc[j][s], 0, 0, 0);
        }
      }
      #pragma unroll
      for (int j=0;j<MAXC;++j) bcur[j] = bnxt[j];
    }
    #pragma unroll 1
    for (int c=0; c<10; ++c){
      // prefetch B(c, ks=0) -- hides under spline compute + 2 barriers
      #pragma unroll
      for (int j=0;j<MAXC;++j) if (j<cnt)
        bcur[j] = *(const short8*)&Bmat[(size_t)((ntlo+j)*16+m16)*1472 + 192 + c*128 + q4*8];
      __syncthreads();   // (at c=0 also: all abase reads done before asp overwrite)
      for (int idx=tid; idx<512; idx+=256){
        const int row = idx>>3, il = idx&7;
        const float xv = xs[row][c*8 + il];
        float bs[8]; spline8(xv, bs);
        union { u16 us[16]; short8 v2[2]; } pk;
        #pragma unroll
        for (int j=0; j<8; ++j){ const u16 hi = f2bf(bs[j]); pk.us[2*j] = hi; pk.us[2*j+1] = f2bf(bs[j] - bf2f(hi)); }
        *(short8*)&asp[row][il*16]     = pk.v2[0];
        *(short8*)&asp[row][il*16 + 8] = pk.v2[1];
      }
      __syncthreads();
      #pragma unroll 1
      for (int ks=0; ks<4; ++ks){
        #pragma unroll
        for (int j=0;j<MAXC;++j) if (j<cnt && ks<3)
          bnxt[j] = *(const short8*)&Bmat[(size_t)((ntlo+j)*16+m16)*1472 + 192 + c*128 + (ks+1)*32 + q4*8];
        short8 a[4];
        #pragma unroll
        for (int s=0;s<4;++s) a[s] = *(const short8*)&asp[s*16+m16][ks*32 + q4*8];
        #pragma unroll
        for (int j=0;j<MAXC;++j){
          if (j < cnt){
            #pragma unroll
            for (int s=0;s<4;++s) acc[j][s] = __builtin_amdgcn_mfma_f32_16x16x32_bf16(a[s], bcur[j], acc[j][s], 0, 0, 0);
          }
        }
        #pragma unroll
        for (int j=0;j<MAXC;++j) bcur[j] = bnxt[j];
      }
    }
    // epilogue: kan1 -> overwrite xs in LDS (xs inputs are dead after c=9);
    // kan2 -> activation + store to Obuf
    __syncthreads();   // ensure all waves done reading xs (spline c=9) before overwrite
    #pragma unroll
    for (int j=0;j<MAXC;++j){
      if (j < cnt){
        const int col = (ntlo+j)*16 + m16;
        #pragma unroll
        for (int s=0;s<4;++s){
          #pragma unroll
          for (int rg=0; rg<4; ++rg){
            const int row = s*16 + q4*4 + rg;
            const float v = acc[j][s][rg];
            if constexpr (!FINAL){
              xs[row][col] = v;          // col < 80 for NT=5
            } else {
              if (col < 257){
                const float sl = lodf(slope, col, isbf);
                const float o = 1.2f * sigm(sl*v);
                if (isbf) ((u16*)Obuf)[(r0+row)*257 + col] = f2bf(o);
                else      ((float*)Obuf)[(r0+row)*257 + col] = o;
              }
            }
          }
        }
      }
    }
    __syncthreads();   // xs writes (and last asp reads) visible before next phase's silu
  };

  phase(IC<5>{},  IC<0>{}, B2mat);
  phase(IC<17>{}, IC<1>{}, B3mat);
}

// ============================= launcher =============================
extern "C" void kernel_launch(void* const* d_in, const int* in_sizes, int n_in,
                              void* d_out, int out_size, void* d_ws, size_t ws_size,
                              hipStream_t stream)
{
  (void)in_sizes; (void)n_in; (void)out_size; (void)ws_size;
  const void* x     = d_in[0];
  const void* f0Wih = d_in[2];  const void* f0Whh = d_in[3];
  const void* f0bih = d_in[4];  const void* f0bhh = d_in[5];
  const void* f1Wih = d_in[6];  const void* f1Whh = d_in[7];
  const void* f1bih = d_in[8];  const void* f1bhh = d_in[9];
  const void* b0Wih = d_in[10]; const void* b0Whh = d_in[11];
  const void* b0bih = d_in[12]; const void* b0bhh = d_in[13];
  const void* b1Wih = d_in[14]; const void* b1Whh = d_in[15];
  const void* b1bih = d_in[16]; const void* b1bhh = d_in[17];
  const void* k1b   = d_in[18]; const void* k1s   = d_in[19]; const void* k1sc = d_in[20];
  const void* k2b   = d_in[21]; const void* k2s   = d_in[22]; const void* k2sc = d_in[23];
  const void* slope = d_in[24];

  char* ws = (char*)d_ws;
  int*   flag  = (int*)(ws + OFF_FLAG);
  float* gi    = (float*)(ws + OFF_GI);
  float* hcat  = (float*)(ws + OFF_HCAT);
  u16* B1a = (u16*)(ws + OFF_B1A);
  u16* B1b = (u16*)(ws + OFF_B1B);
  u16* B2  = (u16*)(ws + OFF_B2);
  u16* B3  = (u16*)(ws + OFF_B3);

  detect_kernel<<<1, 64, 0, stream>>>((const u16*)x, flag);
  prep_kernel<<<1300, 256, 0, stream>>>(f0Wih, b0Wih, k1b, k1s, k1sc, k2b, k2s, k2sc, flag, B1a, B1b, B2, B3);
  g1_kernel<<<1200, 256, 0, stream>>>(x, B1a, B1b, f0bih, b0bih, flag, gi);
  gru_kernel<<<128, 256, 0, stream>>>(gi,
      f0Whh, f0bhh, f1Wih, f1Whh, f1bih, f1bhh,
      b0Whh, b0bhh, b1Wih, b1Whh, b1bih, b1bhh, flag, hcat);
  kan_fused_kernel<<<600, 256, 0, stream>>>(hcat, B2, B3, d_out, slope, flag);
}

// Round 10
// 581.256 us; speedup vs baseline: 1.2622x; 1.1214x over previous
//
#include <hip/hip_runtime.h>
#include <cstdint>
#include <cstddef>

typedef unsigned short u16;
typedef unsigned int u32;
typedef __attribute__((ext_vector_type(8))) short short8;
typedef __attribute__((ext_vector_type(4))) float floatx4;
typedef __attribute__((ext_vector_type(2))) float float2v;

#define NROWS 38400   // B*T = 64*600

// ---- workspace layout (bytes) ----
#define OFF_FLAG 0u
#define OFF_GI   64u           // [2][38400][120] f32 = 36,864,000
#define OFF_HCAT 36864064u     // [38400][80] f32    = 12,288,000
#define OFF_B1A  49152064u     // [256][576] bf16    =    294,912
#define OFF_B1B  49446976u     // [256][576] bf16    =    294,912
#define OFF_B2   49741888u     // [80][1472] bf16    =    235,520
#define OFF_B3   49977408u     // [272][1472] bf16   =    800,768  (end ~50.78 MB)

template<int N> struct IC { static constexpr int v = N; };

__device__ inline float bf2f(u16 u){ union{u32 i; float f;} v; v.i = ((u32)u)<<16; return v.f; }
__device__ inline u16 f2bf(float f){
  u32 u = __float_as_uint(f);
  return (u16)((u + 0x7FFFu + ((u>>16)&1u)) >> 16);   // RNE
}
__device__ inline float lodf(const void* p, size_t i, int isbf){
  return isbf ? bf2f(((const u16*)p)[i]) : ((const float*)p)[i];
}
__device__ inline float rcpf(float x){ return __builtin_amdgcn_rcpf(x); }
__device__ inline float sigm(float x){ return rcpf(1.0f+__expf(-x)); }
__device__ inline float tanh_(float x){
  float e = __expf(-2.0f*fabsf(x)); float t = (1.0f-e)*rcpf(1.0f+e); return x<0.f ? -t : t;
}

// ============================= detect input dtype (bf16 vs f32) =============================
__global__ void detect_kernel(const u16* __restrict__ xx, int* __restrict__ flag){
  const int l = threadIdx.x;
  const u16 w = xx[2*l];
  const int e = (w>>7)&0xFF;
  const unsigned long long m = __ballot(e >= 100 && e <= 133);
  if (l == 0) *flag = (__popcll(m) >= 32) ? 1 : 0;   // 1 = bf16
}

// ============================= prep: build padded bf16 B^T matrices =============================
__global__ void prep_kernel(const void* __restrict__ f0Wih, const void* __restrict__ b0Wih,
                            const void* __restrict__ k1b, const void* __restrict__ k1s, const void* __restrict__ k1sc,
                            const void* __restrict__ k2b, const void* __restrict__ k2s, const void* __restrict__ k2sc,
                            const int* __restrict__ flag,
                            u16* __restrict__ B1a, u16* __restrict__ B1b,
                            u16* __restrict__ B2, u16* __restrict__ B3)
{
  const int isbf = *flag;
  const int idx = blockIdx.x*256 + threadIdx.x;
  if (idx < 73728){
    const int j = idx/288, k = idx - j*288;
    float w = 0.f;
    if (k < 257 && j < 240)
      w = (j < 120) ? lodf(f0Wih, (size_t)j*257+k, isbf) : lodf(b0Wih, (size_t)(j-120)*257+k, isbf);
    const u16 hi = f2bf(w); const u16 lo = f2bf(w - bf2f(hi));
    B1a[(size_t)j*576 + 2*k] = hi; B1a[(size_t)j*576 + 2*k+1] = hi;
    B1b[(size_t)j*576 + 2*k] = lo; B1b[(size_t)j*576 + 2*k+1] = 0;
  } else if (idx < 132608){
    const int t = idx - 73728; const int n = t/736, m = t - n*736;
    float v = 0.f;
    if (m < 80) v = lodf(k1b, (size_t)n*80+m, isbf);
    else if (m >= 96){ const int m2 = m-96, i = m2>>3, g = m2&7;
      v = lodf(k1s, ((size_t)n*80+i)*8+g, isbf) * lodf(k1sc, (size_t)n*80+i, isbf); }
    const u16 vv = f2bf(v);
    B2[(size_t)n*1472 + 2*m] = vv; B2[(size_t)n*1472 + 2*m+1] = vv;
  } else {
    const int t = idx - 132608; const int n = t/736, m = t - n*736;
    float v = 0.f;
    if (n < 257){
      if (m < 80) v = lodf(k2b, (size_t)n*80+m, isbf);
      else if (m >= 96){ const int m2 = m-96, i = m2>>3, g = m2&7;
        v = lodf(k2s, ((size_t)n*80+i)*8+g, isbf) * lodf(k2sc, (size_t)n*80+i, isbf); }
    }
    const u16 vv = f2bf(v);
    B3[(size_t)n*1472 + 2*m] = vv; B3[(size_t)n*1472 + 2*m+1] = vv;
  }
}

// ============================= G1: gi = x @ Wih^T + bih, MFMA, nt-split across waves =============================
// R10: batched 1-deep B prefetch -- all-j fragments for ks+1 issued before
// ks's MFMAs (was: load->MFMA fully serial per j, ~200cy L2 latency exposed
// 72x per wave). As stays padded to 584 u16/row (292 dw == 4 mod 32).
__launch_bounds__(256)
__global__ void g1_kernel(const void* __restrict__ x, const u16* __restrict__ B1a, const u16* __restrict__ B1b,
                          const void* __restrict__ f0bih, const void* __restrict__ b0bih,
                          const int* __restrict__ flag, float* __restrict__ gi)
{
  __shared__ __attribute__((aligned(16))) u16 As[32][584];
  const int isbf = *flag;
  const int tid = threadIdx.x;
  const size_t r0 = (size_t)blockIdx.x * 32;
  const int w = tid>>6, l = tid&63, m16 = l&15, q4 = l>>4;
  // NT=15 split {4,4,4,3}
  const int cnt = (w<3)?4:3;
  const int ntlo = w*4;

  short8 bz;
  #pragma unroll
  for (int q=0;q<8;++q) bz[q]=0;
  short8 baC[4], bbC[4], baN[4], bbN[4];
  #pragma unroll
  for (int j=0;j<4;++j){ baC[j]=bz; bbC[j]=bz; baN[j]=bz; bbN[j]=bz; }
  // prologue prefetch (ks=0) -- overlaps the staging loop below
  #pragma unroll
  for (int j=0;j<4;++j) if (j<cnt){
    baC[j] = *(const short8*)&B1a[(size_t)((ntlo+j)*16+m16)*576 + q4*8];
    if (!isbf) bbC[j] = *(const short8*)&B1b[(size_t)((ntlo+j)*16+m16)*576 + q4*8];
  }

  {
    const int row = tid>>3, kk = tid&7;
    #pragma unroll
    for (int it=0; it<36; ++it){
      const int k = kk + it*8;
      const float v = (k < 257) ? lodf(x, (r0+row)*257 + k, isbf) : 0.f;
      const u16 hi = f2bf(v);
      As[row][2*k] = hi; As[row][2*k+1] = f2bf(v - bf2f(hi));
    }
  }
  __syncthreads();

  floatx4 acc[4][2];
  #pragma unroll
  for (int j=0;j<4;++j) for (int s=0;s<2;++s){ floatx4 z={0.f,0.f,0.f,0.f}; acc[j][s]=z; }
  #pragma unroll 1
  for (int ks=0; ks<18; ++ks){
    if (ks < 17){
      #pragma unroll
      for (int j=0;j<4;++j) if (j<cnt){
        baN[j] = *(const short8*)&B1a[(size_t)((ntlo+j)*16+m16)*576 + (ks+1)*32 + q4*8];
        if (!isbf) bbN[j] = *(const short8*)&B1b[(size_t)((ntlo+j)*16+m16)*576 + (ks+1)*32 + q4*8];
      }
    }
    const short8 a0 = *(const short8*)&As[m16][ks*32 + q4*8];
    const short8 a1 = *(const short8*)&As[16+m16][ks*32 + q4*8];
    #pragma unroll
    for (int j=0;j<4;++j){
      if (j < cnt){
        acc[j][0] = __builtin_amdgcn_mfma_f32_16x16x32_bf16(a0, baC[j], acc[j][0], 0, 0, 0);
        acc[j][1] = __builtin_amdgcn_mfma_f32_16x16x32_bf16(a1, baC[j], acc[j][1], 0, 0, 0);
        if (!isbf){
          acc[j][0] = __builtin_amdgcn_mfma_f32_16x16x32_bf16(a0, bbC[j], acc[j][0], 0, 0, 0);
          acc[j][1] = __builtin_amdgcn_mfma_f32_16x16x32_bf16(a1, bbC[j], acc[j][1], 0, 0, 0);
        }
      }
    }
    #pragma unroll
    for (int j=0;j<4;++j){ baC[j]=baN[j]; bbC[j]=bbN[j]; }
  }
  #pragma unroll
  for (int j=0;j<4;++j){
    if (j < cnt){
      const int col = (ntlo+j)*16 + m16;
      if (col < 240){
        const int dsel = (col < 120) ? 0 : 1;
        const int jj = (col < 120) ? col : col-120;
        const float bias = (col < 120) ? lodf(f0bih, col, isbf) : lodf(b0bih, col-120, isbf);
        #pragma unroll
        for (int s=0;s<2;++s){
          #pragma unroll
          for (int rg=0; rg<4; ++rg){
            const size_t row = r0 + s*16 + q4*4 + rg;
            gi[((size_t)dsel*NROWS + row)*120 + jj] = acc[j][s][rg] + bias;
          }
        }
      }
    }
  }
}

// ============================= GRU (unchanged from R9) =============================
#define PIN_W() do { \
    _Pragma("unroll") \
    for (int k_ = 0; k_ < 20; ++k_) \
      asm volatile("" : "+v"(WA[k_]), "+v"(WB[k_]), "+v"(WC[k_])); \
    asm volatile("" : "+v"(bA), "+v"(bB), "+v"(bC)); \
  } while (0)

__device__ inline void stage_chunk32(const char* __restrict__ gid, int4* dst, int c, int d, int bat, int l)
{
  const long long rbase = (long long)bat*600 + (d ? (568 - 32*c) : (32*c));
  const long long base = rbase * 480;
  const long long lim = (long long)NROWS * 480;
  int4 v[15];
  #pragma unroll
  for (int j=0; j<15; ++j){
    const long long off = base + (long long)(j*64 + l)*16;
    int4 z; z.x=0; z.y=0; z.z=0; z.w=0;
    v[j] = (off >= 0 && off+16 <= lim) ? *(const int4*)(gid + off) : z;
  }
  #pragma unroll
  for (int j=0; j<15; ++j) dst[j*64 + l] = v[j];
}

__launch_bounds__(256, 1)
__global__ void gru_kernel(const float* __restrict__ gi,
  const void* __restrict__ f0Whh, const void* __restrict__ f0bhh,
  const void* __restrict__ f1Wih, const void* __restrict__ f1Whh, const void* __restrict__ f1bih, const void* __restrict__ f1bhh,
  const void* __restrict__ b0Whh, const void* __restrict__ b0bhh,
  const void* __restrict__ b1Wih, const void* __restrict__ b1Whh, const void* __restrict__ b1bih, const void* __restrict__ b1bhh,
  const int* __restrict__ flag, float* __restrict__ hcat)
{
  __shared__ int4 chunkbuf[2][960];                                   // 30720 B
  __shared__ __attribute__((aligned(16))) float hbuf[2][64][40];      // 20480 B
  __shared__ __attribute__((aligned(16))) float h0buf[2][4][40];      // 1280 B
  __shared__ __attribute__((aligned(16))) float gi1buf[2][4][3][40];  // 3840 B
  __shared__ __attribute__((aligned(16))) float h0st[40];             // layer0 h state (broadcast row)
  __shared__ __attribute__((aligned(16))) float h1st[40];             // layer1 h state
  const int isbf = *flag;
  const int tid = threadIdx.x, l = tid&63;
  const int w = __builtin_amdgcn_readfirstlane(tid) >> 6;
  const int blk = blockIdx.x, d = blk>>6, bat = blk&63;
  const int li = (l < 40) ? l : 39;
  const char* gid = (const char*)(gi + (size_t)d*NROWS*120);

  if (w == 3){
    stage_chunk32(gid, &chunkbuf[0][0], 0, d, bat, l);
    __syncthreads();
    #pragma unroll 1
    for (int i=0; i<152; ++i){
      if ((i & 7) == 0){ const int c1 = (i>>3) + 1; if (c1 <= 18) stage_chunk32(gid, &chunkbuf[c1&1][0], c1, d, bat, l); }
      if ((i & 15) == 2 && i >= 18){
        const int m = (i>>4) - 1;
        const int t0 = 64*m;
        const int4* src = (const int4*)&hbuf[m&1][0][0];
        #pragma unroll
        for (int q=0; q<10; ++q){
          const int f = q*64 + l;
          const int t = f/10, j4 = f - 10*t;
          int4 v = src[t*10 + j4];
          *(int4*)&hcat[((size_t)bat*600 + t0 + t)*80 + d*40 + j4*4] = v;
        }
      }
      __syncthreads();
    }
  } else {
    const void *Wsrc = 0, *bsrc = 0;
    if (w == 0){ Wsrc = d ? b0Whh : f0Whh; bsrc = d ? b0bhh : f0bhh; }
    else if (w == 1){ Wsrc = d ? b1Wih : f1Wih; bsrc = d ? b1bih : f1bih; }
    else { Wsrc = d ? b1Whh : f1Whh; bsrc = d ? b1bhh : f1bhh; }

    float2v WA[20], WB[20], WC[20];
    #pragma unroll
    for (int k=0; k<20; ++k){
      WA[k][0] = lodf(Wsrc, (size_t)(     li)*40 + 2*k,   isbf);
      WA[k][1] = lodf(Wsrc, (size_t)(     li)*40 + 2*k+1, isbf);
      WB[k][0] = lodf(Wsrc, (size_t)(40 + li)*40 + 2*k,   isbf);
      WB[k][1] = lodf(Wsrc, (size_t)(40 + li)*40 + 2*k+1, isbf);
      WC[k][0] = lodf(Wsrc, (size_t)(80 + li)*40 + 2*k,   isbf);
      WC[k][1] = lodf(Wsrc, (size_t)(80 + li)*40 + 2*k+1, isbf);
    }
    float bA = lodf(bsrc, li, isbf), bB = lodf(bsrc, 40+li, isbf), bC = lodf(bsrc, 80+li, isbf);
    float hs = 0.f;

    auto mv3B = [&](const float* hrow, float& oa, float& ob, float& oc){
      float2v a2 = {bA, 0.f}, b2 = {bB, 0.f}, c2 = {bC, 0.f};
      #pragma unroll
      for (int kq=0; kq<10; ++kq){
        const floatx4 hv = *(const floatx4*)(hrow + kq*4);
        float2v h0; h0[0]=hv[0]; h0[1]=hv[1];
        float2v h1; h1[0]=hv[2]; h1[1]=hv[3];
        asm("v_pk_fma_f32 %0, %1, %2, %0" : "+v"(a2) : "v"(WA[2*kq  ]), "v"(h0));
        asm("v_pk_fma_f32 %0, %1, %2, %0" : "+v"(b2) : "v"(WB[2*kq  ]), "v"(h0));
        asm("v_pk_fma_f32 %0, %1, %2, %0" : "+v"(c2) : "v"(WC[2*kq  ]), "v"(h0));
        asm("v_pk_fma_f32 %0, %1, %2, %0" : "+v"(a2) : "v"(WA[2*kq+1]), "v"(h1));
        asm("v_pk_fma_f32 %0, %1, %2, %0" : "+v"(b2) : "v"(WB[2*kq+1]), "v"(h1));
        asm("v_pk_fma_f32 %0, %1, %2, %0" : "+v"(c2) : "v"(WC[2*kq+1]), "v"(h1));
      }
      oa = a2[0] + a2[1]; ob = b2[0] + b2[1]; oc = c2[0] + c2[1];
    };
    auto cellB = [&](const float* hrow, float hsv, float gA, float gB, float gC) -> float {
      float ar, az, an;
      mv3B(hrow, ar, az, an);
      const float r = sigm(gA + ar), z = sigm(gB + az);
      const float n = tanh_(gC + r*an);
      return (1.f - z)*n + z*hsv;
    };

    if (w == 0){
      if (l < 40) h0st[l] = 0.f;
      __syncthreads();
      #pragma unroll 1
      for (int i=0; i<152; ++i){
        PIN_W();
        if (i < 150){
          const int cc = (i>>3)&1;
          const int ta = (4*i)&31;
          const float* base = (const float*)&chunkbuf[cc][0];
          float gin[4][3];
          #pragma unroll
          for (int t=0; t<4; ++t){
            const float* r = base + (d ? (31-(ta+t)) : (ta+t))*120;
            gin[t][0]=r[li]; gin[t][1]=r[40+li]; gin[t][2]=r[80+li];
          }
          #pragma unroll
          for (int t=0; t<4; ++t){
            hs = cellB(h0st, hs, gin[t][0], gin[t][1], gin[t][2]);
            if (l < 40){ h0st[l] = hs; h0buf[i&1][t][l] = hs; }
          }
        }
        __syncthreads();
      }
    } else if (w == 1){
      __syncthreads();
      #pragma unroll 1
      for (int i=0; i<152; ++i){
        PIN_W();
        if (i >= 1 && i <= 150){
          const int p = (i-1)&1;
          #pragma unroll
          for (int t=0; t<4; ++t){
            float oa, ob, oc;
            mv3B(&h0buf[p][t][0], oa, ob, oc);
            if (l < 40){
              gi1buf[i&1][t][0][l]=oa; gi1buf[i&1][t][1][l]=ob; gi1buf[i&1][t][2][l]=oc;
            }
          }
        }
        __syncthreads();
      }
    } else {
      if (l < 40) h1st[l] = 0.f;
      __syncthreads();
      #pragma unroll 1
      for (int i=0; i<152; ++i){
        PIN_W();
        if (i >= 2){
          const int p = (i-1)&1;
          float gin[4][3];
          #pragma unroll
          for (int t=0; t<4; ++t){
            gin[t][0]=gi1buf[p][t][0][li]; gin[t][1]=gi1buf[p][t][1][li]; gin[t][2]=gi1buf[p][t][2][li];
          }
          const int ta2 = 4*(i-2);
          const int wp = (ta2>>6)&1, sa = ta2&63;
          #pragma unroll
          for (int t=0; t<4; ++t){
            hs = cellB(h1st, hs, gin[t][0], gin[t][1], gin[t][2]);
            if (l < 40){ h1st[l] = hs; hbuf[wp][sa+t][l] = hs; }
          }
        }
        __syncthreads();
      }
    }
  }
  if (tid < 240){
    const int t = tid/10, j4 = tid - 10*t;
    const int4* src = (const int4*)&hbuf[1][0][0];
    int4 v = src[t*10 + j4];
    *(int4*)&hcat[((size_t)bat*600 + 576 + t)*80 + d*40 + j4*4] = v;
  }
}

// ============================= KAN: fused kan1+kan2 =============================
// R10: (1) 2-deep B prefetch (bcur/bmid/bnxt) -- 10-15 loads in flight/wave
// covers the ~200cy L2 latency fully (1-deep covered ~80cy). (2) asp double-
// buffered: spline(c+1) computed DURING MFMA(c) (disjoint bufs), 1 barrier/c
// instead of 2 (21 -> 12 barriers/phase). (3) closed-form uniform cubic
// B-spline (4 nonzero cardinal bases) replaces the generic Cox-de Boor
// recursion (~170 -> ~70 VALU ops); identical on this uniform grid, and C2
// continuity makes knot-boundary rounding immaterial. asp buf0 aliases abase
// (dead after the 6-ks loop); buf1 separate. LDS 64.5KB -> 2 blocks/CU, which
// R9 proved costs nothing at 600 blocks (2.34 blocks/CU grid limit).
__launch_bounds__(256)
__global__ void kan_fused_kernel(const float* __restrict__ Xin,
                                 const u16* __restrict__ B2mat, const u16* __restrict__ B3mat,
                                 void* __restrict__ Obuf,
                                 const void* __restrict__ slope, const int* __restrict__ flag)
{
  __shared__ __attribute__((aligned(16))) float xs[64][84];       // 21504 B (stride 84 dw == 20 mod 32)
  __shared__ __attribute__((aligned(16))) u16 abase[64][200];     // 25600 B (stride 100 dw == 4 mod 32)
  __shared__ __attribute__((aligned(16))) u16 asp1[64][136];      // 17408 B (stride 68 dw == 4 mod 32)
  const int isbf = *flag;
  const int tid = threadIdx.x;
  const size_t r0 = (size_t)blockIdx.x * 64;
  const int w = tid>>6, l = tid&63, m16 = l&15, q4 = l>>4;

  for (int idx=tid; idx<5120; idx+=256){
    const int row = idx/80, m = idx - row*80;
    xs[row][m] = Xin[r0*80 + idx];
  }
  __syncthreads();

  // closed-form uniform cubic B-spline into dst (512 items, 2/thread)
  auto spline_block = [&](int c, u16 (*dst)[136]){
    #pragma unroll
    for (int h=0; h<2; ++h){
      const int idx = tid + h*256;
      const int row = idx>>3, il = idx&7;
      const float xv = xs[row][c*8 + il];
      const float t  = (xv + 2.2f) * 2.5f;          // (x - g0)/h, g0=-2.2, h=0.4
      const float mf = fminf(fmaxf(floorf(t), -4.f), 14.f);
      const int   m  = (int)mf;
      const float u  = t - mf;
      const float u2 = u*u, u3 = u2*u;
      const float i6 = 1.0f/6.0f;
      const float w1mu = 1.f - u;
      const float n0 = w1mu*w1mu*w1mu*i6;
      const float n1 = (3.f*u3 - 6.f*u2 + 4.f)*i6;
      const float n2 = (-3.f*u3 + 3.f*u2 + 3.f*u + 1.f)*i6;
      const float n3 = u3*i6;
      const bool ok = (t >= 0.f) && (t < 11.f);
      union { u16 us[16]; short8 v2[2]; } pk;
      #pragma unroll
      for (int j=0; j<8; ++j){
        const int s = j + 3 - m;
        float v = 0.f;
        v = (s==0) ? n0 : v;
        v = (s==1) ? n1 : v;
        v = (s==2) ? n2 : v;
        v = (s==3) ? n3 : v;
        v = ok ? v : 0.f;
        const u16 hi = f2bf(v);
        pk.us[2*j] = hi; pk.us[2*j+1] = f2bf(v - bf2f(hi));
      }
      *(short8*)&dst[row][il*16]     = pk.v2[0];
      *(short8*)&dst[row][il*16 + 8] = pk.v2[1];
    }
  };

  auto phase = [&](auto ntc, auto fc, const u16* __restrict__ Bmat){
    constexpr int NT   = decltype(ntc)::v;
    constexpr int FINAL = decltype(fc)::v;
    constexpr int MAXC = (NT+3)/4;
    const int cbase = NT>>2, rem = NT&3;
    const int cnt  = cbase + ((w < rem) ? 1 : 0);
    const int ntlo = w*cbase + ((w < rem) ? w : rem);

    short8 bz;
    #pragma unroll
    for (int q=0;q<8;++q) bz[q]=0;
    short8 bcur[MAXC], bmid[MAXC], bnxt[MAXC];
    #pragma unroll
    for (int j=0;j<MAXC;++j){ bcur[j]=bz; bmid[j]=bz; bnxt[j]=bz; }

    // prefetch base ks=0,1 -- hides under silu + barrier
    #pragma unroll
    for (int j=0;j<MAXC;++j) if (j<cnt){
      bcur[j] = *(const short8*)&Bmat[(size_t)((ntlo+j)*16+m16)*1472 + 0*32 + q4*8];
      bmid[j] = *(const short8*)&Bmat[(size_t)((ntlo+j)*16+m16)*1472 + 1*32 + q4*8];
    }

    // silu(xs) -> abase (hi/lo bf16 pairs)
    for (int idx=tid; idx<6144; idx+=256){
      const int row = idx/96, m = idx - row*96;
      float v = 0.f;
      if (m < 80){ const float xv = xs[row][m]; v = xv * sigm(xv); }
      const u16 hi = f2bf(v);
      abase[row][2*m] = hi; abase[row][2*m+1] = f2bf(v - bf2f(hi));
    }
    __syncthreads();

    floatx4 acc[MAXC][4];
    #pragma unroll
    for (int j=0;j<MAXC;++j) for (int s=0;s<4;++s){ floatx4 z={0.f,0.f,0.f,0.f}; acc[j][s]=z; }

    // ---- base section: 6 ks on abase, 2-deep prefetch ----
    #pragma unroll 1
    for (int ks=0; ks<6; ++ks){
      if (ks < 4){
        #pragma unroll
        for (int j=0;j<MAXC;++j) if (j<cnt)
          bnxt[j] = *(const short8*)&Bmat[(size_t)((ntlo+j)*16+m16)*1472 + (ks+2)*32 + q4*8];
      }
      short8 a[4];
      #pragma unroll
      for (int s=0;s<4;++s) a[s] = *(const short8*)&abase[s*16+m16][ks*32 + q4*8];
      #pragma unroll
      for (int j=0;j<MAXC;++j){
        if (j < cnt){
          #pragma unroll
          for (int s=0;s<4;++s) acc[j][s] = __builtin_amdgcn_mfma_f32_16x16x32_bf16(a[s], bcur[j], acc[j][s], 0, 0, 0);
        }
      }
      #pragma unroll
      for (int j=0;j<MAXC;++j){ bcur[j]=bmid[j]; bmid[j]=bnxt[j]; }
    }
    __syncthreads();                   // all abase reads done before asp buf0 (alias) write

    // prefetch c-loop (c=0, ks=0/1); then spline(0) -> buf0 (abase alias)
    #pragma unroll
    for (int j=0;j<MAXC;++j) if (j<cnt){
      bcur[j] = *(const short8*)&Bmat[(size_t)((ntlo+j)*16+m16)*1472 + 192 + 0*128 + 0*32 + q4*8];
      bmid[j] = *(const short8*)&Bmat[(size_t)((ntlo+j)*16+m16)*1472 + 192 + 0*128 + 1*32 + q4*8];
    }
    spline_block(0, (u16(*)[136])&abase[0][0]);
    __syncthreads();                   // asp buf0 visible

    #pragma unroll 1
    for (int c=0; c<10; ++c){
      // spline(c+1) into the OTHER buffer: overlaps this c's MFMAs
      if (c < 9) spline_block(c+1, ((c+1)&1) ? asp1 : (u16(*)[136])&abase[0][0]);
      const u16 (*aspr)[136] = (c&1) ? (const u16(*)[136])asp1 : (const u16(*)[136])&abase[0][0];
      #pragma unroll 1
      for (int ks=0; ks<4; ++ks){
        const int pos = c*4 + ks + 2;          // 2-deep flat prefetch position
        if (pos < 40){
          const int pc = pos>>2, pk = pos&3;
          #pragma unroll
          for (int j=0;j<MAXC;++j) if (j<cnt)
            bnxt[j] = *(const short8*)&Bmat[(size_t)((ntlo+j)*16+m16)*1472 + 192 + pc*128 + pk*32 + q4*8];
        }
        short8 a[4];
        #pragma unroll
        for (int s=0;s<4;++s) a[s] = *(const short8*)&aspr[s*16+m16][ks*32 + q4*8];
        #pragma unroll
        for (int j=0;j<MAXC;++j){
          if (j < cnt){
            #pragma unroll
            for (int s=0;s<4;++s) acc[j][s] = __builtin_amdgcn_mfma_f32_16x16x32_bf16(a[s], bcur[j], acc[j][s], 0, 0, 0);
          }
        }
        #pragma unroll
        for (int j=0;j<MAXC;++j){ bcur[j]=bmid[j]; bmid[j]=bnxt[j]; }
      }
      __syncthreads();                 // spline(c+1) ready; MFMA(c) reads retired
    }

    // epilogue: kan1 -> overwrite xs in LDS; kan2 -> activation + store
    #pragma unroll
    for (int j=0;j<MAXC;++j){
      if (j < cnt){
        const int col = (ntlo+j)*16 + m16;
        #pragma unroll
        for (int s=0;s<4;++s){
          #pragma unroll
          for (int rg=0; rg<4; ++rg){
            const int row = s*16 + q4*4 + rg;
            const float v = acc[j][s][rg];
            if constexpr (!FINAL){
              xs[row][col] = v;          // col < 80 for NT=5
            } else {
              if (col < 257){
                const float sl = lodf(slope, col, isbf);
                const float o = 1.2f * sigm(sl*v);
                if (isbf) ((u16*)Obuf)[(r0+row)*257 + col] = f2bf(o);
                else      ((float*)Obuf)[(r0+row)*257 + col] = o;
              }
            }
          }
        }
      }
    }
    __syncthreads();   // xs writes visible before next phase's silu reads
  };

  phase(IC<5>{},  IC<0>{}, B2mat);
  phase(IC<17>{}, IC<1>{}, B3mat);
}

// ============================= launcher =============================
extern "C" void kernel_launch(void* const* d_in, const int* in_sizes, int n_in,
                              void* d_out, int out_size, void* d_ws, size_t ws_size,
                              hipStream_t stream)
{
  (void)in_sizes; (void)n_in; (void)out_size; (void)ws_size;
  const void* x     = d_in[0];
  const void* f0Wih = d_in[2];  const void* f0Whh = d_in[3];
  const void* f0bih = d_in[4];  const void* f0bhh = d_in[5];
  const void* f1Wih = d_in[6];  const void* f1Whh = d_in[7];
  const void* f1bih = d_in[8];  const void* f1bhh = d_in[9];
  const void* b0Wih = d_in[10]; const void* b0Whh = d_in[11];
  const void* b0bih = d_in[12]; const void* b0bhh = d_in[13];
  const void* b1Wih = d_in[14]; const void* b1Whh = d_in[15];
  const void* b1bih = d_in[16]; const void* b1bhh = d_in[17];
  const void* k1b   = d_in[18]; const void* k1s   = d_in[19]; const void* k1sc = d_in[20];
  const void* k2b   = d_in[21]; const void* k2s   = d_in[22]; const void* k2sc = d_in[23];
  const void* slope = d_in[24];

  char* ws = (char*)d_ws;
  int*   flag  = (int*)(ws + OFF_FLAG);
  float* gi    = (float*)(ws + OFF_GI);
  float* hcat  = (float*)(ws + OFF_HCAT);
  u16* B1a = (u16*)(ws + OFF_B1A);
  u16* B1b = (u16*)(ws + OFF_B1B);
  u16* B2  = (u16*)(ws + OFF_B2);
  u16* B3  = (u16*)(ws + OFF_B3);

  detect_kernel<<<1, 64, 0, stream>>>((const u16*)x, flag);
  prep_kernel<<<1300, 256, 0, stream>>>(f0Wih, b0Wih, k1b, k1s, k1sc, k2b, k2s, k2sc, flag, B1a, B1b, B2, B3);
  g1_kernel<<<1200, 256, 0, stream>>>(x, B1a, B1b, f0bih, b0bih, flag, gi);
  gru_kernel<<<128, 256, 0, stream>>>(gi,
      f0Whh, f0bhh, f1Wih, f1Whh, f1bih, f1bhh,
      b0Whh, b0bhh, b1Wih, b1Whh, b1bih, b1bhh, flag, hcat);
  kan_fused_kernel<<<600, 256, 0, stream>>>(hcat, B2, B3, d_out, slope, flag);
}